// Round 2
// baseline (875.863 us; speedup 1.0000x reference)
//
#include <hip/hip_runtime.h>
#include <math.h>

namespace {

constexpr int kNME  = 262144;
constexpr int kNDOF = 524288;
constexpr int kNNZ  = kNME * 64;

constexpr float kEmin    = 1e-9f;
constexpr float kEmax    = 1.0f;
constexpr float kVolfrac = 0.4f;

constexpr int kMaxRep = 16;   // max Ku replicas (power of 2)

// ---------------------------------------------------------------------------
// Kernel 1: per-element SIMP scale + rho partial sum.
// ---------------------------------------------------------------------------
__global__ void scale_kernel(const float* __restrict__ W_x,
                             float* __restrict__ scale,
                             float* __restrict__ rho_sum) {
    int i = blockIdx.x * blockDim.x + threadIdx.x;
    float rho = 0.0f;
    if (i < kNME) {
        float x = W_x[i];
        rho = 1.0f / (1.0f + __expf(-x));
        float s = kEmin + rho * rho * rho * (kEmax - kEmin);
        scale[i] = s;
    }
    for (int off = 32; off > 0; off >>= 1) rho += __shfl_down(rho, off, 64);
    __shared__ float partial[4];
    const int lane = threadIdx.x & 63;
    const int wid  = threadIdx.x >> 6;
    if (lane == 0) partial[wid] = rho;
    __syncthreads();
    if (threadIdx.x == 0) {
        float t = partial[0] + partial[1] + partial[2] + partial[3];
        atomicAdd(rho_sum, t);
    }
}

// ---------------------------------------------------------------------------
// Kernel 2: COO scatter into a replicated accumulator.
// Each block adds into replica (blockIdx & (nrep-1)) -> per-line contention /nrep.
// Streaming operands use nontemporal loads so u/Ku stay cache-resident.
// ---------------------------------------------------------------------------
__global__ void scatter_kernel(const float* __restrict__ K_sep,
                               const int*   __restrict__ rows,
                               const int*   __restrict__ cols,
                               const float* __restrict__ u,
                               const float* __restrict__ scale,
                               float* __restrict__ Ku,     // nrep * kNDOF
                               int nrep_mask) {
    int i = blockIdx.x * blockDim.x + threadIdx.x;
    if (i >= kNNZ) return;
    float* ku = Ku + ((size_t)(blockIdx.x & nrep_mask) * kNDOF);
    float s = scale[i >> 6];                       // wave-uniform broadcast
    float k = __builtin_nontemporal_load(&K_sep[i]);
    int   r = __builtin_nontemporal_load(&rows[i]);
    int   c = __builtin_nontemporal_load(&cols[i]);
    float v = k * s * u[c];
    atomicAdd(&ku[r], v);
}

// ---------------------------------------------------------------------------
// Kernel 3: sum of ((sum_r Ku_r) - f)^2
// ---------------------------------------------------------------------------
__global__ void norm_kernel(const float* __restrict__ Ku,
                            const float* __restrict__ f,
                            float* __restrict__ norm_sum,
                            int nrep) {
    float acc = 0.0f;
    for (int i = blockIdx.x * blockDim.x + threadIdx.x; i < kNDOF;
         i += gridDim.x * blockDim.x) {
        float s = 0.0f;
        for (int r = 0; r < nrep; ++r) s += Ku[(size_t)r * kNDOF + i];
        float d = s - f[i];
        acc += d * d;
    }
    for (int off = 32; off > 0; off >>= 1) acc += __shfl_down(acc, off, 64);
    __shared__ float partial[4];
    const int lane = threadIdx.x & 63;
    const int wid  = threadIdx.x >> 6;
    if (lane == 0) partial[wid] = acc;
    __syncthreads();
    if (threadIdx.x == 0) {
        float t = partial[0] + partial[1] + partial[2] + partial[3];
        atomicAdd(norm_sum, t);
    }
}

// ---------------------------------------------------------------------------
// Kernel 4: finalize scalar loss
// ---------------------------------------------------------------------------
__global__ void finalize_kernel(const float* __restrict__ acc,
                                float* __restrict__ out) {
    if (threadIdx.x == 0 && blockIdx.x == 0) {
        float rho_mean = acc[0] * (1.0f / (float)kNME);
        float vol = fmaxf(rho_mean - kVolfrac, 0.0f);
        out[0] = vol + sqrtf(acc[1]);
    }
}

}  // namespace

extern "C" void kernel_launch(void* const* d_in, const int* in_sizes, int n_in,
                              void* d_out, int out_size, void* d_ws, size_t ws_size,
                              hipStream_t stream) {
    const float* W_x   = (const float*)d_in[0];
    const float* K_sep = (const float*)d_in[1];
    const int*   idx   = (const int*)d_in[2];   // (2, NNZ) row-major
    const float* u     = (const float*)d_in[3];
    const float* f     = (const float*)d_in[4];
    const int* rows = idx;
    const int* cols = idx + kNNZ;

    // Workspace layout (floats): scale[kNME] | acc[2] pad to 16 | Ku replicas
    float* ws    = (float*)d_ws;
    float* scale = ws;
    float* acc   = ws + kNME;
    float* Ku    = ws + kNME + 16;

    // How many power-of-2 replicas fit in the workspace?
    size_t avail_floats = ws_size / sizeof(float);
    int nrep = 1;
    while (nrep < kMaxRep &&
           (size_t)(kNME + 16) + (size_t)(nrep * 2) * kNDOF <= avail_floats)
        nrep *= 2;

    // Zero acc + all Ku replicas (every call: replay-safe).
    hipMemsetAsync(acc, 0,
                   (size_t)(16 + (size_t)nrep * kNDOF) * sizeof(float), stream);

    scale_kernel<<<(kNME + 255) / 256, 256, 0, stream>>>(W_x, scale, acc);

    scatter_kernel<<<(kNNZ + 255) / 256, 256, 0, stream>>>(
        K_sep, rows, cols, u, scale, Ku, nrep - 1);

    norm_kernel<<<2048, 256, 0, stream>>>(Ku, f, acc + 1, nrep);

    finalize_kernel<<<1, 64, 0, stream>>>(acc, (float*)d_out);
}

// Round 3
// 867.376 us; speedup vs baseline: 1.0098x; 1.0098x over previous
//
#include <hip/hip_runtime.h>
#include <math.h>

namespace {

constexpr int kNME  = 262144;
constexpr int kNDOF = 524288;
constexpr int kNNZ  = kNME * 64;
constexpr int kNXCD = 8;

constexpr float kEmin    = 1e-9f;
constexpr float kEmax    = 1.0f;
constexpr float kVolfrac = 0.4f;

__device__ __forceinline__ int xcc_id() {
    int x;
    asm volatile("s_getreg_b32 %0, hwreg(HW_REG_XCC_ID)" : "=s"(x));
    return x & 7;
}

// ---------------------------------------------------------------------------
// Kernel 1: per-element SIMP scale + rho partial sum.
// ---------------------------------------------------------------------------
__global__ void scale_kernel(const float* __restrict__ W_x,
                             float* __restrict__ scale,
                             float* __restrict__ rho_sum) {
    int i = blockIdx.x * blockDim.x + threadIdx.x;
    float rho = 0.0f;
    if (i < kNME) {
        float x = W_x[i];
        rho = 1.0f / (1.0f + __expf(-x));
        float s = kEmin + rho * rho * rho * (kEmax - kEmin);
        scale[i] = s;
    }
    for (int off = 32; off > 0; off >>= 1) rho += __shfl_down(rho, off, 64);
    __shared__ float partial[4];
    const int lane = threadIdx.x & 63;
    const int wid  = threadIdx.x >> 6;
    if (lane == 0) partial[wid] = rho;
    __syncthreads();
    if (threadIdx.x == 0) {
        float t = partial[0] + partial[1] + partial[2] + partial[3];
        atomicAdd(rho_sum, t);
    }
}

// ---------------------------------------------------------------------------
// Kernel 2a: COO scatter, XCD-local replicas + workgroup-scope atomics.
// Each XCD owns replica xcc_id(); the atomic RMW stays in the local TCC
// (no cross-die coherence round-trip).
// ---------------------------------------------------------------------------
__global__ void scatter_xcd_kernel(const float* __restrict__ K_sep,
                                   const int*   __restrict__ rows,
                                   const int*   __restrict__ cols,
                                   const float* __restrict__ u,
                                   const float* __restrict__ scale,
                                   float* __restrict__ Ku) {  // kNXCD * kNDOF
    int i = blockIdx.x * blockDim.x + threadIdx.x;
    if (i >= kNNZ) return;
    float* ku = Ku + (size_t)xcc_id() * kNDOF;
    float s = scale[i >> 6];                       // wave-uniform broadcast
    float k = __builtin_nontemporal_load(&K_sep[i]);
    int   r = __builtin_nontemporal_load(&rows[i]);
    int   c = __builtin_nontemporal_load(&cols[i]);
    float v = k * s * u[c];
    __hip_atomic_fetch_add(&ku[r], v, __ATOMIC_RELAXED,
                           __HIP_MEMORY_SCOPE_WORKGROUP);
}

// ---------------------------------------------------------------------------
// Kernel 2b: fallback — device-scope atomics, single accumulator.
// ---------------------------------------------------------------------------
__global__ void scatter_dev_kernel(const float* __restrict__ K_sep,
                                   const int*   __restrict__ rows,
                                   const int*   __restrict__ cols,
                                   const float* __restrict__ u,
                                   const float* __restrict__ scale,
                                   float* __restrict__ Ku) {
    int i = blockIdx.x * blockDim.x + threadIdx.x;
    if (i >= kNNZ) return;
    float s = scale[i >> 6];
    float k = __builtin_nontemporal_load(&K_sep[i]);
    int   r = __builtin_nontemporal_load(&rows[i]);
    int   c = __builtin_nontemporal_load(&cols[i]);
    atomicAdd(&Ku[r], k * s * u[c]);
}

// ---------------------------------------------------------------------------
// Kernel 3: sum of ((sum_r Ku_r) - f)^2
// ---------------------------------------------------------------------------
__global__ void norm_kernel(const float* __restrict__ Ku,
                            const float* __restrict__ f,
                            float* __restrict__ norm_sum,
                            int nrep) {
    float acc = 0.0f;
    for (int i = blockIdx.x * blockDim.x + threadIdx.x; i < kNDOF;
         i += gridDim.x * blockDim.x) {
        float s = 0.0f;
        #pragma unroll 8
        for (int r = 0; r < nrep; ++r) s += Ku[(size_t)r * kNDOF + i];
        float d = s - f[i];
        acc += d * d;
    }
    for (int off = 32; off > 0; off >>= 1) acc += __shfl_down(acc, off, 64);
    __shared__ float partial[4];
    const int lane = threadIdx.x & 63;
    const int wid  = threadIdx.x >> 6;
    if (lane == 0) partial[wid] = acc;
    __syncthreads();
    if (threadIdx.x == 0) {
        float t = partial[0] + partial[1] + partial[2] + partial[3];
        atomicAdd(norm_sum, t);
    }
}

// ---------------------------------------------------------------------------
// Kernel 4: finalize scalar loss
// ---------------------------------------------------------------------------
__global__ void finalize_kernel(const float* __restrict__ acc,
                                float* __restrict__ out) {
    if (threadIdx.x == 0 && blockIdx.x == 0) {
        float rho_mean = acc[0] * (1.0f / (float)kNME);
        float vol = fmaxf(rho_mean - kVolfrac, 0.0f);
        out[0] = vol + sqrtf(acc[1]);
    }
}

}  // namespace

extern "C" void kernel_launch(void* const* d_in, const int* in_sizes, int n_in,
                              void* d_out, int out_size, void* d_ws, size_t ws_size,
                              hipStream_t stream) {
    const float* W_x   = (const float*)d_in[0];
    const float* K_sep = (const float*)d_in[1];
    const int*   idx   = (const int*)d_in[2];   // (2, NNZ) row-major
    const float* u     = (const float*)d_in[3];
    const float* f     = (const float*)d_in[4];
    const int* rows = idx;
    const int* cols = idx + kNNZ;

    // Workspace layout (floats): scale[kNME] | acc[16] | Ku replicas
    float* ws    = (float*)d_ws;
    float* scale = ws;
    float* acc   = ws + kNME;
    float* Ku    = ws + kNME + 16;

    size_t avail_floats = ws_size / sizeof(float);
    bool xcd_path =
        (size_t)(kNME + 16) + (size_t)kNXCD * kNDOF <= avail_floats;
    int nrep = xcd_path ? kNXCD : 1;

    // Zero acc + Ku replicas (every call: replay-safe).
    hipMemsetAsync(acc, 0,
                   (size_t)(16 + (size_t)nrep * kNDOF) * sizeof(float), stream);

    scale_kernel<<<(kNME + 255) / 256, 256, 0, stream>>>(W_x, scale, acc);

    if (xcd_path) {
        scatter_xcd_kernel<<<(kNNZ + 255) / 256, 256, 0, stream>>>(
            K_sep, rows, cols, u, scale, Ku);
    } else {
        scatter_dev_kernel<<<(kNNZ + 255) / 256, 256, 0, stream>>>(
            K_sep, rows, cols, u, scale, Ku);
    }

    norm_kernel<<<2048, 256, 0, stream>>>(Ku, f, acc + 1, nrep);

    finalize_kernel<<<1, 64, 0, stream>>>(acc, (float*)d_out);
}

// Round 4
// 572.897 us; speedup vs baseline: 1.5288x; 1.5140x over previous
//
#include <hip/hip_runtime.h>
#include <math.h>

namespace {

constexpr int       kNME   = 262144;
constexpr int       kNDOF  = 524288;
constexpr long long kNNZ   = 16777216;   // kNME * 64
constexpr int       kNB    = 128;        // buckets
constexpr int       kBShift = 12;        // 4096 dofs / bucket
constexpr int       kBSpan  = 4096;

constexpr float kEmin    = 1e-9f;
constexpr float kEmax    = 1.0f;
constexpr float kVolfrac = 0.4f;

// ---------------------------------------------------------------------------
// Kernel 1: per-element SIMP scale + rho partial sum.
// ---------------------------------------------------------------------------
__global__ void scale_kernel(const float* __restrict__ W_x,
                             float* __restrict__ scale,
                             float* __restrict__ rho_sum) {
    int i = blockIdx.x * blockDim.x + threadIdx.x;
    float rho = 0.0f;
    if (i < kNME) {
        float x = W_x[i];
        rho = 1.0f / (1.0f + __expf(-x));
        scale[i] = kEmin + rho * rho * rho * (kEmax - kEmin);
    }
    for (int off = 32; off > 0; off >>= 1) rho += __shfl_down(rho, off, 64);
    __shared__ float partial[4];
    const int lane = threadIdx.x & 63;
    const int wid  = threadIdx.x >> 6;
    if (lane == 0) partial[wid] = rho;
    __syncthreads();
    if (threadIdx.x == 0)
        atomicAdd(rho_sum, partial[0] + partial[1] + partial[2] + partial[3]);
}

// ---------------------------------------------------------------------------
// Producer: stream entries, bucket by row>>12, write (local_row, v) pairs
// into per-bucket regions.  Global atomics: kNB per BLOCK (range reserve).
// Per-entry accumulation atomics are LDS-only.
// ---------------------------------------------------------------------------
__global__ void producer_kernel(const float* __restrict__ K_sep,
                                const int*   __restrict__ rows,
                                const int*   __restrict__ cols,
                                const float* __restrict__ u,
                                const float* __restrict__ scale,
                                uint2*       __restrict__ pairs,
                                unsigned*    __restrict__ counters,  // [kNB], this chunk
                                long long chunk_base, int cap) {
    __shared__ unsigned hist[kNB], bbase[kNB], loc[kNB];
    const int tid = threadIdx.x;
    if (tid < kNB) { hist[tid] = 0u; loc[tid] = 0u; }
    __syncthreads();

    const long long base = chunk_base + (long long)blockIdx.x * 16384;

    // pass 1: histogram of bucket ids (rows only)
    for (int j = 0; j < 64; ++j) {
        int r = rows[base + (long long)j * 256 + tid];
        atomicAdd(&hist[r >> kBShift], 1u);
    }
    __syncthreads();
    // reserve output ranges: one global int atomic per bucket per block
    if (tid < kNB) bbase[tid] = atomicAdd(&counters[tid], hist[tid]);
    __syncthreads();

    // pass 2: compute values, place into bucket regions
    for (int j = 0; j < 64; ++j) {
        long long i = base + (long long)j * 256 + tid;
        int   r = rows[i];
        int   c = cols[i];
        float k = K_sep[i];
        float s = scale[(int)(i >> 6)];          // wave-uniform broadcast
        float v = k * s * u[c];
        int   b = r >> kBShift;
        unsigned slot = atomicAdd(&loc[b], 1u) + bbase[b];
        if (slot < (unsigned)cap)
            pairs[(size_t)b * cap + slot] =
                make_uint2((unsigned)(r & (kBSpan - 1)), __float_as_uint(v));
    }
}

// ---------------------------------------------------------------------------
// Consumer: grid = kNB * R blocks.  Block (b, rep) accumulates its slice of
// bucket b's pairs into a 16 KB LDS tile (ds_add_f32), then adds the tile
// into its privately-owned global partial (no atomics).
// ---------------------------------------------------------------------------
__global__ void consumer_kernel(const uint2*    __restrict__ pairs,
                                const unsigned* __restrict__ counters,
                                float*          __restrict__ partial,
                                int cap, int R) {
    const int b   = blockIdx.x / R;
    const int rep = blockIdx.x % R;
    unsigned cnt = counters[b];
    if (cnt > (unsigned)cap) cnt = (unsigned)cap;
    const unsigned lo = (unsigned)(((unsigned long long)cnt * rep) / R);
    const unsigned hi = (unsigned)(((unsigned long long)cnt * (rep + 1)) / R);

    __shared__ float acc[kBSpan];
    for (int i = threadIdx.x; i < kBSpan; i += 256) acc[i] = 0.0f;
    __syncthreads();

    const uint2* p = pairs + (size_t)b * cap;
    for (unsigned i = lo + threadIdx.x; i < hi; i += 256) {
        uint2 e = p[i];
        atomicAdd(&acc[e.x], __uint_as_float(e.y));   // LDS atomic
    }
    __syncthreads();

    float* dst = partial + ((size_t)b * R + rep) * kBSpan;
    for (int i = threadIdx.x; i < kBSpan; i += 256) dst[i] += acc[i];
}

// ---------------------------------------------------------------------------
// Norm: Ku[d] = sum over R partials; accumulate (Ku-f)^2.
// ---------------------------------------------------------------------------
__global__ void norm_kernel(const float* __restrict__ partial,
                            const float* __restrict__ f,
                            float* __restrict__ norm_sum, int R) {
    float a = 0.0f;
    for (int d = blockIdx.x * blockDim.x + threadIdx.x; d < kNDOF;
         d += gridDim.x * blockDim.x) {
        const float* pp = partial + (size_t)(d >> kBShift) * R * kBSpan +
                          (d & (kBSpan - 1));
        float s = 0.0f;
        for (int r = 0; r < R; ++r) s += pp[(size_t)r * kBSpan];
        float dd = s - f[d];
        a += dd * dd;
    }
    for (int off = 32; off > 0; off >>= 1) a += __shfl_down(a, off, 64);
    __shared__ float partial_s[4];
    const int lane = threadIdx.x & 63;
    const int wid  = threadIdx.x >> 6;
    if (lane == 0) partial_s[wid] = a;
    __syncthreads();
    if (threadIdx.x == 0)
        atomicAdd(norm_sum,
                  partial_s[0] + partial_s[1] + partial_s[2] + partial_s[3]);
}

// ---------------------------------------------------------------------------
// Fallback scatter (device atomics) if workspace is too small.
// ---------------------------------------------------------------------------
__global__ void scatter_dev_kernel(const float* __restrict__ K_sep,
                                   const int*   __restrict__ rows,
                                   const int*   __restrict__ cols,
                                   const float* __restrict__ u,
                                   const float* __restrict__ scale,
                                   float* __restrict__ Ku) {
    long long i = (long long)blockIdx.x * blockDim.x + threadIdx.x;
    if (i >= kNNZ) return;
    float s = scale[(int)(i >> 6)];
    atomicAdd(&Ku[rows[i]], K_sep[i] * s * u[cols[i]]);
}

__global__ void norm1_kernel(const float* __restrict__ Ku,
                             const float* __restrict__ f,
                             float* __restrict__ norm_sum) {
    float a = 0.0f;
    for (int i = blockIdx.x * blockDim.x + threadIdx.x; i < kNDOF;
         i += gridDim.x * blockDim.x) {
        float d = Ku[i] - f[i];
        a += d * d;
    }
    for (int off = 32; off > 0; off >>= 1) a += __shfl_down(a, off, 64);
    __shared__ float partial_s[4];
    const int lane = threadIdx.x & 63;
    const int wid  = threadIdx.x >> 6;
    if (lane == 0) partial_s[wid] = a;
    __syncthreads();
    if (threadIdx.x == 0)
        atomicAdd(norm_sum,
                  partial_s[0] + partial_s[1] + partial_s[2] + partial_s[3]);
}

__global__ void finalize_kernel(const float* __restrict__ acc,
                                float* __restrict__ out) {
    if (threadIdx.x == 0 && blockIdx.x == 0) {
        float rho_mean = acc[0] * (1.0f / (float)kNME);
        float vol = fmaxf(rho_mean - kVolfrac, 0.0f);
        out[0] = vol + sqrtf(acc[1]);
    }
}

}  // namespace

extern "C" void kernel_launch(void* const* d_in, const int* in_sizes, int n_in,
                              void* d_out, int out_size, void* d_ws, size_t ws_size,
                              hipStream_t stream) {
    const float* W_x   = (const float*)d_in[0];
    const float* K_sep = (const float*)d_in[1];
    const int*   idx   = (const int*)d_in[2];
    const float* u     = (const float*)d_in[3];
    const float* f     = (const float*)d_in[4];
    const int* rows = idx;
    const int* cols = idx + kNNZ;

    float* ws = (float*)d_ws;
    const size_t avail = ws_size / sizeof(float);

    // Pick (num_chunks, R) — smallest chunking that fits the workspace.
    struct Opt { int nc, R; };
    const Opt opts[] = {{1, 4}, {2, 4}, {4, 4}, {8, 2}, {16, 2}};
    int NC = -1, R = 4;
    long long cap = 0;
    const size_t off_partial = 16 + 16 * kNB;   // acc + counters (16 chunk rows)
    size_t partialF = 0;
    for (const Opt& o : opts) {
        long long chunk = kNNZ / o.nc;
        long long mcap  = chunk / kNB + 2048 + chunk / 2048;  // mean + big margin
        size_t pf   = (size_t)kNB * o.R * kBSpan;
        size_t need = off_partial + pf + kNME + (size_t)kNB * (size_t)mcap * 2;
        if (need <= avail) { NC = o.nc; R = o.R; cap = mcap; partialF = pf; break; }
    }

    if (NC < 0) {
        // Fallback: device-atomic scatter (fits in ~3.2 MB).
        float* Ku    = ws;                    // kNDOF
        float* scale = ws + kNDOF;            // kNME
        float* acc   = ws + kNDOF + kNME;     // 2
        hipMemsetAsync(ws, 0, (size_t)(kNDOF + kNME + 16) * sizeof(float), stream);
        scale_kernel<<<kNME / 256, 256, 0, stream>>>(W_x, scale, acc);
        scatter_dev_kernel<<<(int)(kNNZ / 256), 256, 0, stream>>>(
            K_sep, rows, cols, u, scale, Ku);
        norm1_kernel<<<2048, 256, 0, stream>>>(Ku, f, acc + 1);
        finalize_kernel<<<1, 64, 0, stream>>>(acc, (float*)d_out);
        return;
    }

    float*    acc      = ws;                         // [16]
    unsigned* counters = (unsigned*)(ws + 16);       // [16][kNB]
    float*    partial  = ws + off_partial;           // [kNB*R*kBSpan]
    float*    scale    = partial + partialF;         // [kNME]
    uint2*    pairs    = (uint2*)(scale + kNME);     // [kNB * cap]

    // Zero acc + counters + partial every call (replay-safe).
    hipMemsetAsync(ws, 0, (off_partial + partialF) * sizeof(float), stream);

    scale_kernel<<<kNME / 256, 256, 0, stream>>>(W_x, scale, acc);

    const long long chunk = kNNZ / NC;
    const int prod_blocks = (int)(chunk / 16384);
    for (int c = 0; c < NC; ++c) {
        producer_kernel<<<prod_blocks, 256, 0, stream>>>(
            K_sep, rows, cols, u, scale, pairs, counters + (size_t)c * kNB,
            chunk * c, (int)cap);
        consumer_kernel<<<kNB * R, 256, 0, stream>>>(
            pairs, counters + (size_t)c * kNB, partial, (int)cap, R);
    }

    norm_kernel<<<2048, 256, 0, stream>>>(partial, f, acc + 1, R);

    finalize_kernel<<<1, 64, 0, stream>>>(acc, (float*)d_out);
}

// Round 6
// 341.322 us; speedup vs baseline: 2.5661x; 1.6785x over previous
//
#include <hip/hip_runtime.h>
#include <math.h>

namespace {

constexpr int       kNME    = 262144;
constexpr int       kNDOF   = 524288;
constexpr long long kNNZ    = 16777216;   // kNME * 64
constexpr int       kNB     = 64;         // buckets
constexpr int       kBShift = 13;         // 8192 dofs / bucket
constexpr int       kBSpan  = 8192;
constexpr int       kEnt    = 4096;       // entries per producer block
constexpr int       kPerTh  = 16;         // kEnt / 256
constexpr int       kCtrStride = 16;      // counters padded to 64 B lines

constexpr float kEmin    = 1e-9f;
constexpr float kEmax    = 1.0f;
constexpr float kVolfrac = 0.4f;

using u64 = unsigned long long;

__device__ __forceinline__ u64 pack(unsigned localrow, float v) {
    return ((u64)localrow << 32) | (u64)__float_as_uint(v);
}

// ---------------------------------------------------------------------------
// Kernel 1: per-element SIMP scale + rho partial sum.
// ---------------------------------------------------------------------------
__global__ void scale_kernel(const float* __restrict__ W_x,
                             float* __restrict__ scale,
                             float* __restrict__ rho_sum) {
    int i = blockIdx.x * blockDim.x + threadIdx.x;
    float rho = 0.0f;
    if (i < kNME) {
        float x = W_x[i];
        rho = 1.0f / (1.0f + __expf(-x));
        scale[i] = kEmin + rho * rho * rho * (kEmax - kEmin);
    }
    for (int off = 32; off > 0; off >>= 1) rho += __shfl_down(rho, off, 64);
    __shared__ float partial[4];
    const int lane = threadIdx.x & 63;
    const int wid  = threadIdx.x >> 6;
    if (lane == 0) partial[wid] = rho;
    __syncthreads();
    if (threadIdx.x == 0)
        atomicAdd(rho_sum, partial[0] + partial[1] + partial[2] + partial[3]);
}

// ---------------------------------------------------------------------------
// Producer: per-block counting sort in LDS, then COALESCED per-bucket run
// writes.  Entries held in registers (fully unrolled, static indices).
// Global atomics: kNB per block, on 64B-padded counters.
// ---------------------------------------------------------------------------
__global__ __launch_bounds__(256)
void producer_kernel(const float* __restrict__ K_sep,
                     const int*   __restrict__ rows,
                     const int*   __restrict__ cols,
                     const float* __restrict__ u,
                     const float* __restrict__ scale,
                     u64*         __restrict__ pairs,
                     unsigned*    __restrict__ counters,   // [kNB*kCtrStride]
                     long long chunk_base, unsigned cap) {
    __shared__ unsigned hist[kNB];
    __shared__ unsigned ofs[kNB];
    __shared__ unsigned cursor[kNB];
    __shared__ unsigned gbase[kNB];
    __shared__ u64      sorted[kEnt];     // 32 KB

    const int tid = threadIdx.x;
    if (tid < kNB) { hist[tid] = 0u; cursor[tid] = 0u; }
    __syncthreads();

    const long long base = chunk_base + (long long)blockIdx.x * kEnt;

    unsigned rr[kPerTh];
    float    vv[kPerTh];
#pragma unroll
    for (int j = 0; j < kPerTh; ++j) {
        long long i = base + (long long)j * 256 + tid;
        int   r = __builtin_nontemporal_load(&rows[i]);
        int   c = __builtin_nontemporal_load(&cols[i]);
        float k = __builtin_nontemporal_load(&K_sep[i]);
        float s = scale[(int)(i >> 6)];          // wave-uniform
        rr[j] = (unsigned)r;
        vv[j] = k * s * u[c];
        atomicAdd(&hist[(unsigned)r >> kBShift], 1u);
    }
    __syncthreads();

    // Exclusive prefix over 64 buckets in wave 0 + reserve global ranges.
    if (tid < kNB) {
        unsigned h = hist[tid];
        unsigned x = h;
#pragma unroll
        for (int off = 1; off < kNB; off <<= 1) {
            unsigned y = __shfl_up(x, off, 64);
            if (tid >= off) x += y;
        }
        ofs[tid]   = x - h;                                   // exclusive scan
        gbase[tid] = atomicAdd(&counters[tid * kCtrStride], h);
    }
    __syncthreads();

    // Scatter into sorted LDS order (LDS cursors, LDS writes only).
#pragma unroll
    for (int j = 0; j < kPerTh; ++j) {
        unsigned b = rr[j] >> kBShift;
        unsigned p = ofs[b] + atomicAdd(&cursor[b], 1u);
        sorted[p] = pack(rr[j] & (kBSpan - 1), vv[j]);
    }
    __syncthreads();

    // Coalesced copy-out: one wave per bucket run.
    const int wid = tid >> 6, lane = tid & 63;
    for (int b = wid; b < kNB; b += 4) {
        const unsigned s0 = ofs[b];
        const unsigned n  = hist[b];
        const unsigned g  = gbase[b];
        u64* dst = pairs + (size_t)b * cap + g;
        for (unsigned i = lane; i < n; i += 64) {
            if (g + i < cap)
                __builtin_nontemporal_store(sorted[s0 + i], &dst[i]);
        }
    }
}

// ---------------------------------------------------------------------------
// Consumer: block (b, rep) accumulates its slice of bucket b's pairs into a
// 32 KB LDS tile (ds_add_f32), then adds into its private global partial.
// ---------------------------------------------------------------------------
__global__ __launch_bounds__(256)
void consumer_kernel(const u64*      __restrict__ pairs,
                     const unsigned* __restrict__ counters,
                     float*          __restrict__ partial,
                     unsigned cap, int R) {
    const int b   = blockIdx.x / R;
    const int rep = blockIdx.x - b * R;
    unsigned cnt = counters[b * kCtrStride];
    if (cnt > cap) cnt = cap;
    const unsigned lo = (unsigned)(((unsigned long long)cnt * rep) / R);
    const unsigned hi = (unsigned)(((unsigned long long)cnt * (rep + 1)) / R);

    __shared__ float acc[kBSpan];
    for (int i = threadIdx.x; i < kBSpan; i += 256) acc[i] = 0.0f;
    __syncthreads();

    const u64* p = pairs + (size_t)b * cap;
    for (unsigned i = lo + threadIdx.x; i < hi; i += 256) {
        u64 e = __builtin_nontemporal_load(&p[i]);
        atomicAdd(&acc[e >> 32], __uint_as_float((unsigned)e));   // LDS atomic
    }
    __syncthreads();

    float* dst = partial + ((size_t)b * R + rep) * kBSpan;
    for (int i = threadIdx.x; i < kBSpan; i += 256) dst[i] += acc[i];
}

// ---------------------------------------------------------------------------
// Norm: Ku[d] = sum over R partials; accumulate (Ku-f)^2.
// ---------------------------------------------------------------------------
__global__ void norm_kernel(const float* __restrict__ partial,
                            const float* __restrict__ f,
                            float* __restrict__ norm_sum, int R) {
    float a = 0.0f;
    for (int d = blockIdx.x * blockDim.x + threadIdx.x; d < kNDOF;
         d += gridDim.x * blockDim.x) {
        const float* pp = partial + (size_t)(d >> kBShift) * R * kBSpan +
                          (d & (kBSpan - 1));
        float s = 0.0f;
        for (int r = 0; r < R; ++r) s += pp[(size_t)r * kBSpan];
        float dd = s - f[d];
        a += dd * dd;
    }
    for (int off = 32; off > 0; off >>= 1) a += __shfl_down(a, off, 64);
    __shared__ float partial_s[4];
    const int lane = threadIdx.x & 63;
    const int wid  = threadIdx.x >> 6;
    if (lane == 0) partial_s[wid] = a;
    __syncthreads();
    if (threadIdx.x == 0)
        atomicAdd(norm_sum,
                  partial_s[0] + partial_s[1] + partial_s[2] + partial_s[3]);
}

// ---------------------------------------------------------------------------
// Fallback scatter (device atomics) if workspace is too small.
// ---------------------------------------------------------------------------
__global__ void scatter_dev_kernel(const float* __restrict__ K_sep,
                                   const int*   __restrict__ rows,
                                   const int*   __restrict__ cols,
                                   const float* __restrict__ u,
                                   const float* __restrict__ scale,
                                   float* __restrict__ Ku) {
    long long i = (long long)blockIdx.x * blockDim.x + threadIdx.x;
    if (i >= kNNZ) return;
    float s = scale[(int)(i >> 6)];
    atomicAdd(&Ku[rows[i]], K_sep[i] * s * u[cols[i]]);
}

__global__ void norm1_kernel(const float* __restrict__ Ku,
                             const float* __restrict__ f,
                             float* __restrict__ norm_sum) {
    float a = 0.0f;
    for (int i = blockIdx.x * blockDim.x + threadIdx.x; i < kNDOF;
         i += gridDim.x * blockDim.x) {
        float d = Ku[i] - f[i];
        a += d * d;
    }
    for (int off = 32; off > 0; off >>= 1) a += __shfl_down(a, off, 64);
    __shared__ float partial_s[4];
    const int lane = threadIdx.x & 63;
    const int wid  = threadIdx.x >> 6;
    if (lane == 0) partial_s[wid] = a;
    __syncthreads();
    if (threadIdx.x == 0)
        atomicAdd(norm_sum,
                  partial_s[0] + partial_s[1] + partial_s[2] + partial_s[3]);
}

__global__ void finalize_kernel(const float* __restrict__ acc,
                                float* __restrict__ out) {
    if (threadIdx.x == 0 && blockIdx.x == 0) {
        float rho_mean = acc[0] * (1.0f / (float)kNME);
        float vol = fmaxf(rho_mean - kVolfrac, 0.0f);
        out[0] = vol + sqrtf(acc[1]);
    }
}

}  // namespace

extern "C" void kernel_launch(void* const* d_in, const int* in_sizes, int n_in,
                              void* d_out, int out_size, void* d_ws, size_t ws_size,
                              hipStream_t stream) {
    const float* W_x   = (const float*)d_in[0];
    const float* K_sep = (const float*)d_in[1];
    const int*   idx   = (const int*)d_in[2];
    const float* u     = (const float*)d_in[3];
    const float* f     = (const float*)d_in[4];
    const int* rows = idx;
    const int* cols = idx + kNNZ;

    float* ws = (float*)d_ws;
    const size_t avail = ws_size / sizeof(float);

    // Pick (num_chunks, R): first config that fits the workspace.
    struct Opt { int nc, R; };
    const Opt opts[] = {{1, 16}, {1, 8}, {1, 4}, {2, 8}, {4, 8}, {8, 4}, {16, 4}};
    int NC = -1, R = 8;
    unsigned cap = 0;
    size_t ctrF = 0, partialF = 0;
    for (const Opt& o : opts) {
        long long chunk = kNNZ / o.nc;
        unsigned  mcap  = (unsigned)(chunk / kNB + kBSpan);   // mean + 16 sigma
        size_t cf = (size_t)o.nc * kNB * kCtrStride;          // uint == float size
        size_t pf = (size_t)kNB * o.R * kBSpan;
        size_t need = 16 + cf + pf + (size_t)kNME + (size_t)kNB * mcap * 2;
        if (need <= avail) {
            NC = o.nc; R = o.R; cap = mcap; ctrF = cf; partialF = pf;
            break;
        }
    }

    if (NC < 0) {
        // Fallback: device-atomic scatter (fits in ~3.2 MB).
        float* Ku    = ws;
        float* scale = ws + kNDOF;
        float* acc   = ws + kNDOF + kNME;
        hipMemsetAsync(ws, 0, (size_t)(kNDOF + kNME + 16) * sizeof(float), stream);
        scale_kernel<<<kNME / 256, 256, 0, stream>>>(W_x, scale, acc);
        scatter_dev_kernel<<<(int)(kNNZ / 256), 256, 0, stream>>>(
            K_sep, rows, cols, u, scale, Ku);
        norm1_kernel<<<2048, 256, 0, stream>>>(Ku, f, acc + 1);
        finalize_kernel<<<1, 64, 0, stream>>>(acc, (float*)d_out);
        return;
    }

    float*    acc      = ws;                          // [16]
    unsigned* counters = (unsigned*)(ws + 16);        // [NC][kNB*kCtrStride]
    float*    partial  = ws + 16 + ctrF;              // [kNB*R*kBSpan]
    float*    scale    = partial + partialF;          // [kNME]
    u64*      pairs    = (u64*)(scale + kNME);        // [kNB * cap]

    // Zero acc + counters + partial every call (replay-safe).
    hipMemsetAsync(ws, 0, (16 + ctrF + partialF) * sizeof(float), stream);

    scale_kernel<<<kNME / 256, 256, 0, stream>>>(W_x, scale, acc);

    const long long chunk = kNNZ / NC;
    const int prod_blocks = (int)(chunk / kEnt);
    for (int c = 0; c < NC; ++c) {
        producer_kernel<<<prod_blocks, 256, 0, stream>>>(
            K_sep, rows, cols, u, scale, pairs,
            counters + (size_t)c * kNB * kCtrStride, chunk * c, cap);
        consumer_kernel<<<kNB * R, 256, 0, stream>>>(
            pairs, counters + (size_t)c * kNB * kCtrStride, partial, cap, R);
    }

    norm_kernel<<<2048, 256, 0, stream>>>(partial, f, acc + 1, R);

    finalize_kernel<<<1, 64, 0, stream>>>(acc, (float*)d_out);
}

// Round 7
// 289.638 us; speedup vs baseline: 3.0240x; 1.1784x over previous
//
#include <hip/hip_runtime.h>
#include <math.h>

namespace {

constexpr int       kNME    = 262144;
constexpr int       kNDOF   = 524288;
constexpr long long kNNZ    = 16777216;   // kNME * 64
constexpr int       kNB     = 64;         // buckets
constexpr int       kBShift = 13;         // 8192 dofs / bucket
constexpr int       kBSpan  = 8192;
constexpr int       kEnt    = 2048;       // entries per producer block
constexpr int       kPerTh  = 8;          // kEnt / 256
constexpr int       kCtrStride = 16;      // counters padded to 64 B

constexpr float kEmin    = 1e-9f;
constexpr float kEmax    = 1.0f;
constexpr float kVolfrac = 0.4f;

using u64   = unsigned long long;
using i32x4 = __attribute__((ext_vector_type(4))) int;
using f32x4 = __attribute__((ext_vector_type(4))) float;

__device__ __forceinline__ u64 pack(unsigned localrow, float v) {
    return ((u64)localrow << 32) | (u64)__float_as_uint(v);
}

// ---------------------------------------------------------------------------
// Kernel 1: per-element SIMP scale + rho partial sum.
// ---------------------------------------------------------------------------
__global__ void scale_kernel(const float* __restrict__ W_x,
                             float* __restrict__ scale,
                             float* __restrict__ rho_sum) {
    int i = blockIdx.x * blockDim.x + threadIdx.x;
    float rho = 0.0f;
    if (i < kNME) {
        float x = W_x[i];
        rho = 1.0f / (1.0f + __expf(-x));
        scale[i] = kEmin + rho * rho * rho * (kEmax - kEmin);
    }
    for (int off = 32; off > 0; off >>= 1) rho += __shfl_down(rho, off, 64);
    __shared__ float partial[4];
    const int lane = threadIdx.x & 63;
    const int wid  = threadIdx.x >> 6;
    if (lane == 0) partial[wid] = rho;
    __syncthreads();
    if (threadIdx.x == 0)
        atomicAdd(rho_sum, partial[0] + partial[1] + partial[2] + partial[3]);
}

// ---------------------------------------------------------------------------
// Producer: 2048-entry block. Vectorized 16B staging loads, LDS counting
// sort, coalesced per-bucket run copy-out into sub-region (blockIdx & (R-1)).
// ---------------------------------------------------------------------------
__global__ __launch_bounds__(256)
void producer_kernel(const float* __restrict__ K_sep,
                     const int*   __restrict__ rows,
                     const int*   __restrict__ cols,
                     const float* __restrict__ u,
                     const float* __restrict__ scale,
                     u64*         __restrict__ pairs,
                     unsigned*    __restrict__ counters,  // [kNB*R*kCtrStride]
                     long long chunk_base, unsigned capSub, int R) {
    __shared__ unsigned hist[kNB], ofs[kNB], cursor[kNB], gbase[kNB];
    __shared__ u64      sorted[kEnt];     // 16 KB

    const int tid = threadIdx.x;
    const int sub = blockIdx.x & (R - 1);
    if (tid < kNB) { hist[tid] = 0u; cursor[tid] = 0u; }
    __syncthreads();

    // 8 consecutive entries per thread: fully-coalesced 16B vector loads,
    // and all 8 share ONE element scale (8 | 64).
    const long long i0 =
        chunk_base + (long long)blockIdx.x * kEnt + (long long)tid * kPerTh;
    i32x4 r0 = __builtin_nontemporal_load((const i32x4*)(rows + i0));
    i32x4 r1 = __builtin_nontemporal_load((const i32x4*)(rows + i0) + 1);
    i32x4 c0 = __builtin_nontemporal_load((const i32x4*)(cols + i0));
    i32x4 c1 = __builtin_nontemporal_load((const i32x4*)(cols + i0) + 1);
    f32x4 k0 = __builtin_nontemporal_load((const f32x4*)(K_sep + i0));
    f32x4 k1 = __builtin_nontemporal_load((const f32x4*)(K_sep + i0) + 1);
    const float s = scale[(int)(i0 >> 6)];

    unsigned rr[kPerTh];
    float    vv[kPerTh];
#pragma unroll
    for (int j = 0; j < 4; ++j) {
        rr[j]     = (unsigned)r0[j];  vv[j]     = k0[j] * s * u[c0[j]];
        rr[j + 4] = (unsigned)r1[j];  vv[j + 4] = k1[j] * s * u[c1[j]];
    }
#pragma unroll
    for (int j = 0; j < kPerTh; ++j)
        atomicAdd(&hist[rr[j] >> kBShift], 1u);
    __syncthreads();

    // Wave 0: exclusive scan over 64 buckets + reserve global sub-ranges.
    if (tid < kNB) {
        unsigned h = hist[tid];
        unsigned x = h;
#pragma unroll
        for (int off = 1; off < kNB; off <<= 1) {
            unsigned y = __shfl_up(x, off, 64);
            if (tid >= off) x += y;
        }
        ofs[tid]   = x - h;
        gbase[tid] = atomicAdd(&counters[(tid * R + sub) * kCtrStride], h);
    }
    __syncthreads();

    // Scatter into sorted LDS order.
#pragma unroll
    for (int j = 0; j < kPerTh; ++j) {
        unsigned b = rr[j] >> kBShift;
        unsigned p = ofs[b] + atomicAdd(&cursor[b], 1u);
        sorted[p] = pack(rr[j] & (kBSpan - 1), vv[j]);
    }
    __syncthreads();

    // Coalesced copy-out: one wave per bucket run.
    const int wid = tid >> 6, lane = tid & 63;
    for (int b = wid; b < kNB; b += 4) {
        const unsigned s0 = ofs[b];
        const unsigned n  = hist[b];
        const unsigned g  = gbase[b];
        u64* dst = pairs + (size_t)(b * R + sub) * capSub + g;
        for (unsigned i = lane; i < n; i += 64) {
            if (g + i < capSub)
                __builtin_nontemporal_store(sorted[s0 + i], &dst[i]);
        }
    }
}

// ---------------------------------------------------------------------------
// Consumer: block (b, sub) owns one sub-region entirely. Paired 16B loads,
// fire-and-forget LDS atomics, private store of its partial tile.
// ---------------------------------------------------------------------------
__global__ __launch_bounds__(256)
void consumer_kernel(const u64*      __restrict__ pairs,
                     const unsigned* __restrict__ counters,
                     float*          __restrict__ partial,
                     unsigned capSub, int R, int accum) {
    const int b   = blockIdx.x / R;
    const int sub = blockIdx.x - b * R;
    unsigned cnt = counters[(b * R + sub) * kCtrStride];
    if (cnt > capSub) cnt = capSub;

    __shared__ float acc[kBSpan];
    for (int i = threadIdx.x; i < kBSpan; i += 256) acc[i] = 0.0f;
    __syncthreads();

    const u64* p = pairs + (size_t)(b * R + sub) * capSub;
    for (unsigned i = 2 * threadIdx.x; i + 1 < cnt; i += 512) {
        u64 e0 = __builtin_nontemporal_load(&p[i]);
        u64 e1 = __builtin_nontemporal_load(&p[i + 1]);
        atomicAdd(&acc[e0 >> 32], __uint_as_float((unsigned)e0));
        atomicAdd(&acc[e1 >> 32], __uint_as_float((unsigned)e1));
    }
    if ((cnt & 1u) && threadIdx.x == 0) {
        u64 e = p[cnt - 1];
        atomicAdd(&acc[e >> 32], __uint_as_float((unsigned)e));
    }
    __syncthreads();

    float* dst = partial + (size_t)(b * R + sub) * kBSpan;
    if (accum) {
        for (int i = threadIdx.x; i < kBSpan; i += 256) dst[i] += acc[i];
    } else {
        for (int i = threadIdx.x; i < kBSpan; i += 256) dst[i] = acc[i];
    }
}

// ---------------------------------------------------------------------------
// Norm: Ku[d] = sum over R sub-partials; accumulate (Ku-f)^2.
// ---------------------------------------------------------------------------
__global__ void norm_kernel(const float* __restrict__ partial,
                            const float* __restrict__ f,
                            float* __restrict__ norm_sum, int R) {
    float a = 0.0f;
    for (int d = blockIdx.x * blockDim.x + threadIdx.x; d < kNDOF;
         d += gridDim.x * blockDim.x) {
        const float* pp = partial + (size_t)(d >> kBShift) * R * kBSpan +
                          (d & (kBSpan - 1));
        float s = 0.0f;
        for (int r = 0; r < R; ++r) s += pp[(size_t)r * kBSpan];
        float dd = s - f[d];
        a += dd * dd;
    }
    for (int off = 32; off > 0; off >>= 1) a += __shfl_down(a, off, 64);
    __shared__ float partial_s[4];
    const int lane = threadIdx.x & 63;
    const int wid  = threadIdx.x >> 6;
    if (lane == 0) partial_s[wid] = a;
    __syncthreads();
    if (threadIdx.x == 0)
        atomicAdd(norm_sum,
                  partial_s[0] + partial_s[1] + partial_s[2] + partial_s[3]);
}

// ---------------------------------------------------------------------------
// Fallback scatter (device atomics) if workspace is too small.
// ---------------------------------------------------------------------------
__global__ void scatter_dev_kernel(const float* __restrict__ K_sep,
                                   const int*   __restrict__ rows,
                                   const int*   __restrict__ cols,
                                   const float* __restrict__ u,
                                   const float* __restrict__ scale,
                                   float* __restrict__ Ku) {
    long long i = (long long)blockIdx.x * blockDim.x + threadIdx.x;
    if (i >= kNNZ) return;
    float s = scale[(int)(i >> 6)];
    atomicAdd(&Ku[rows[i]], K_sep[i] * s * u[cols[i]]);
}

__global__ void norm1_kernel(const float* __restrict__ Ku,
                             const float* __restrict__ f,
                             float* __restrict__ norm_sum) {
    float a = 0.0f;
    for (int i = blockIdx.x * blockDim.x + threadIdx.x; i < kNDOF;
         i += gridDim.x * blockDim.x) {
        float d = Ku[i] - f[i];
        a += d * d;
    }
    for (int off = 32; off > 0; off >>= 1) a += __shfl_down(a, off, 64);
    __shared__ float partial_s[4];
    const int lane = threadIdx.x & 63;
    const int wid  = threadIdx.x >> 6;
    if (lane == 0) partial_s[wid] = a;
    __syncthreads();
    if (threadIdx.x == 0)
        atomicAdd(norm_sum,
                  partial_s[0] + partial_s[1] + partial_s[2] + partial_s[3]);
}

__global__ void finalize_kernel(const float* __restrict__ acc,
                                float* __restrict__ out) {
    if (threadIdx.x == 0 && blockIdx.x == 0) {
        float rho_mean = acc[0] * (1.0f / (float)kNME);
        float vol = fmaxf(rho_mean - kVolfrac, 0.0f);
        out[0] = vol + sqrtf(acc[1]);
    }
}

}  // namespace

extern "C" void kernel_launch(void* const* d_in, const int* in_sizes, int n_in,
                              void* d_out, int out_size, void* d_ws, size_t ws_size,
                              hipStream_t stream) {
    const float* W_x   = (const float*)d_in[0];
    const float* K_sep = (const float*)d_in[1];
    const int*   idx   = (const int*)d_in[2];
    const float* u     = (const float*)d_in[3];
    const float* f     = (const float*)d_in[4];
    const int* rows = idx;
    const int* cols = idx + kNNZ;

    float* ws = (float*)d_ws;
    const size_t avail = ws_size / sizeof(float);

    // Pick (num_chunks, R, cap margin): first config that fits.
    struct Opt { int nc, R; unsigned margin; };
    const Opt opts[] = {{1, 16, 2048}, {1, 16, 1024}, {1, 8, 2048},
                        {2, 8, 2048},  {2, 8, 1024},  {4, 8, 1024},
                        {4, 4, 1024},  {8, 4, 1024}};
    int NC = -1, R = 16;
    unsigned capSub = 0;
    size_t ctrF = 0, partialF = 0;
    for (const Opt& o : opts) {
        long long perCell = kNNZ / ((long long)o.nc * kNB * o.R);
        unsigned  mc      = (unsigned)perCell + o.margin;
        size_t cf = (size_t)o.nc * kNB * o.R * kCtrStride;
        size_t pf = (size_t)kNB * o.R * kBSpan;
        size_t need = 16 + cf + pf + (size_t)kNME +
                      (size_t)kNB * o.R * (size_t)mc * 2;
        if (need <= avail) {
            NC = o.nc; R = o.R; capSub = mc; ctrF = cf; partialF = pf;
            break;
        }
    }

    if (NC < 0) {
        // Fallback: device-atomic scatter (fits in ~3.2 MB).
        float* Ku    = ws;
        float* scale = ws + kNDOF;
        float* acc   = ws + kNDOF + kNME;
        hipMemsetAsync(ws, 0, (size_t)(kNDOF + kNME + 16) * sizeof(float), stream);
        scale_kernel<<<kNME / 256, 256, 0, stream>>>(W_x, scale, acc);
        scatter_dev_kernel<<<(int)(kNNZ / 256), 256, 0, stream>>>(
            K_sep, rows, cols, u, scale, Ku);
        norm1_kernel<<<2048, 256, 0, stream>>>(Ku, f, acc + 1);
        finalize_kernel<<<1, 64, 0, stream>>>(acc, (float*)d_out);
        return;
    }

    float*    acc      = ws;                          // [16]
    unsigned* counters = (unsigned*)(ws + 16);        // [NC][kNB*R*kCtrStride]
    float*    partial  = ws + 16 + ctrF;              // [kNB*R*kBSpan]
    float*    scale    = partial + partialF;          // [kNME]
    u64*      pairs    = (u64*)(scale + kNME);        // [kNB*R*capSub]

    // Zero acc + counters only (partial is stored, not accumulated, on c=0).
    hipMemsetAsync(ws, 0, (16 + ctrF) * sizeof(float), stream);

    scale_kernel<<<kNME / 256, 256, 0, stream>>>(W_x, scale, acc);

    const long long chunk = kNNZ / NC;
    const int prod_blocks = (int)(chunk / kEnt);
    for (int c = 0; c < NC; ++c) {
        unsigned* ctr = counters + (size_t)c * kNB * R * kCtrStride;
        producer_kernel<<<prod_blocks, 256, 0, stream>>>(
            K_sep, rows, cols, u, scale, pairs, ctr, chunk * c, capSub, R);
        consumer_kernel<<<kNB * R, 256, 0, stream>>>(
            pairs, ctr, partial, capSub, R, /*accum=*/c > 0 ? 1 : 0);
    }

    norm_kernel<<<2048, 256, 0, stream>>>(partial, f, acc + 1, R);

    finalize_kernel<<<1, 64, 0, stream>>>(acc, (float*)d_out);
}

// Round 8
// 258.879 us; speedup vs baseline: 3.3833x; 1.1188x over previous
//
#include <hip/hip_runtime.h>
#include <math.h>

namespace {

constexpr int       kNME    = 262144;
constexpr int       kNDOF   = 524288;
constexpr long long kNNZ    = 16777216;   // kNME * 64
constexpr int       kNB     = 64;         // buckets
constexpr int       kBShift = 13;         // 8192 dofs / bucket
constexpr int       kBSpan  = 8192;
constexpr int       kEnt    = 2048;       // entries per producer block
constexpr int       kPerTh  = 8;          // kEnt / 256
constexpr int       kCtrStride = 16;      // counters padded to 64 B

constexpr float kEmin    = 1e-9f;
constexpr float kEmax    = 1.0f;
constexpr float kVolfrac = 0.4f;

using u32   = unsigned;
using i32x4 = __attribute__((ext_vector_type(4))) int;
using f32x4 = __attribute__((ext_vector_type(4))) float;
using u32x4 = __attribute__((ext_vector_type(4))) unsigned;

// pair = (localrow:13 bits << 19) | (fp32 bits >> 13)  [sign+exp+10 mantissa]
__device__ __forceinline__ u32 pack32(unsigned localrow, float v) {
    return (localrow << 19) | (__float_as_uint(v) >> 13);
}

// ---------------------------------------------------------------------------
// Kernel 1: per-element SIMP scale + rho partial sum.
// ---------------------------------------------------------------------------
__global__ void scale_kernel(const float* __restrict__ W_x,
                             float* __restrict__ scale,
                             float* __restrict__ rho_sum) {
    int i = blockIdx.x * blockDim.x + threadIdx.x;
    float rho = 0.0f;
    if (i < kNME) {
        float x = W_x[i];
        rho = 1.0f / (1.0f + __expf(-x));
        scale[i] = kEmin + rho * rho * rho * (kEmax - kEmin);
    }
    for (int off = 32; off > 0; off >>= 1) rho += __shfl_down(rho, off, 64);
    __shared__ float partial[4];
    const int lane = threadIdx.x & 63;
    const int wid  = threadIdx.x >> 6;
    if (lane == 0) partial[wid] = rho;
    __syncthreads();
    if (threadIdx.x == 0)
        atomicAdd(rho_sum, partial[0] + partial[1] + partial[2] + partial[3]);
}

// ---------------------------------------------------------------------------
// Producer: vectorized staging loads; hist atomicAdd doubles as rank (no
// cursor atomics); 4B packed pairs; coalesced per-bucket run copy-out.
// rv[j] layout: bits[0:18] = row (19b), bits[19:30] = in-block rank (11b).
// ---------------------------------------------------------------------------
__global__ __launch_bounds__(256, 8)
void producer_kernel(const float* __restrict__ K_sep,
                     const int*   __restrict__ rows,
                     const int*   __restrict__ cols,
                     const float* __restrict__ u,
                     const float* __restrict__ scale,
                     u32*         __restrict__ pairs,
                     unsigned*    __restrict__ counters,  // [kNB*R*kCtrStride]
                     long long chunk_base, unsigned capSub, int R) {
    __shared__ unsigned hist[kNB], ofs[kNB], gbase[kNB];
    __shared__ u32      sorted[kEnt];     // 8 KB

    const int tid = threadIdx.x;
    const int sub = blockIdx.x & (R - 1);
    if (tid < kNB) hist[tid] = 0u;
    __syncthreads();

    const long long i0 =
        chunk_base + (long long)blockIdx.x * kEnt + (long long)tid * kPerTh;
    i32x4 r0 = __builtin_nontemporal_load((const i32x4*)(rows + i0));
    i32x4 r1 = __builtin_nontemporal_load((const i32x4*)(rows + i0) + 1);
    i32x4 c0 = __builtin_nontemporal_load((const i32x4*)(cols + i0));
    i32x4 c1 = __builtin_nontemporal_load((const i32x4*)(cols + i0) + 1);
    f32x4 k0 = __builtin_nontemporal_load((const f32x4*)(K_sep + i0));
    f32x4 k1 = __builtin_nontemporal_load((const f32x4*)(K_sep + i0) + 1);
    const float s = scale[(int)(i0 >> 6)];   // all 8 share one element

    unsigned rv[kPerTh];
    float    vv[kPerTh];
#pragma unroll
    for (int j = 0; j < 4; ++j) {
        rv[j]     = (unsigned)r0[j];  vv[j]     = k0[j] * s * u[c0[j]];
        rv[j + 4] = (unsigned)r1[j];  vv[j + 4] = k1[j] * s * u[c1[j]];
    }
    // Histogram; the returned old value IS this entry's rank in its bucket.
#pragma unroll
    for (int j = 0; j < kPerTh; ++j)
        rv[j] |= atomicAdd(&hist[rv[j] >> kBShift], 1u) << 19;
    __syncthreads();

    // Wave 0: exclusive scan over 64 buckets + reserve global sub-ranges.
    if (tid < kNB) {
        unsigned h = hist[tid];
        unsigned x = h;
#pragma unroll
        for (int off = 1; off < kNB; off <<= 1) {
            unsigned y = __shfl_up(x, off, 64);
            if (tid >= off) x += y;
        }
        ofs[tid]   = x - h;
        gbase[tid] = atomicAdd(&counters[(tid * R + sub) * kCtrStride], h);
    }
    __syncthreads();

    // Scatter into sorted LDS order — no atomics (rank precomputed).
#pragma unroll
    for (int j = 0; j < kPerTh; ++j) {
        unsigned row = rv[j] & 0x7FFFFu;
        unsigned b   = row >> kBShift;
        unsigned pos = ofs[b] + (rv[j] >> 19);
        sorted[pos]  = pack32(row & (kBSpan - 1), vv[j]);
    }
    __syncthreads();

    // Coalesced copy-out: one wave per bucket run.
    const int wid = tid >> 6, lane = tid & 63;
    for (int b = wid; b < kNB; b += 4) {
        const unsigned s0 = ofs[b];
        const unsigned n  = hist[b];
        const unsigned g  = gbase[b];
        u32* dst = pairs + (size_t)(b * R + sub) * capSub + g;
        for (unsigned i = lane; i < n; i += 64) {
            if (g + i < capSub)
                __builtin_nontemporal_store(sorted[s0 + i], &dst[i]);
        }
    }
}

// ---------------------------------------------------------------------------
// Consumer: block (b, sub) owns one sub-region. 512 threads, 16B u32x4
// loads, fire-and-forget LDS atomics, private store of its partial tile.
// ---------------------------------------------------------------------------
__global__ __launch_bounds__(512, 8)
void consumer_kernel(const u32*      __restrict__ pairs,
                     const unsigned* __restrict__ counters,
                     float*          __restrict__ partial,
                     unsigned capSub, int R, int accum) {
    const int b   = blockIdx.x / R;
    const int sub = blockIdx.x - b * R;
    unsigned cnt = counters[(b * R + sub) * kCtrStride];
    if (cnt > capSub) cnt = capSub;

    __shared__ float acc[kBSpan];
    for (int i = threadIdx.x; i < kBSpan; i += 512) acc[i] = 0.0f;
    __syncthreads();

    const u32* p = pairs + (size_t)(b * R + sub) * capSub;
    const unsigned aligned = cnt & ~3u;
    for (unsigned i = 4 * threadIdx.x; i < aligned; i += 4 * 512) {
        u32x4 e = __builtin_nontemporal_load((const u32x4*)(p + i));
#pragma unroll
        for (int j = 0; j < 4; ++j)
            atomicAdd(&acc[e[j] >> 19], __uint_as_float(e[j] << 13));
    }
    if (threadIdx.x < (cnt - aligned)) {
        u32 e = p[aligned + threadIdx.x];
        atomicAdd(&acc[e >> 19], __uint_as_float(e << 13));
    }
    __syncthreads();

    float* dst = partial + (size_t)(b * R + sub) * kBSpan;
    if (accum) {
        for (int i = threadIdx.x; i < kBSpan; i += 512) dst[i] += acc[i];
    } else {
        for (int i = threadIdx.x; i < kBSpan; i += 512) dst[i] = acc[i];
    }
}

// ---------------------------------------------------------------------------
// Norm: coalesced — block (b, chunk of 1024 dofs); vectorized sum over the
// R planes, then (Ku-f)^2 reduction.  Grid = kNB * (kBSpan/1024).
// ---------------------------------------------------------------------------
__global__ void norm_kernel(const float* __restrict__ partial,
                            const float* __restrict__ f,
                            float* __restrict__ norm_sum, int R) {
    const int b     = blockIdx.x >> 3;
    const int i0    = (blockIdx.x & 7) * 1024 + threadIdx.x * 4;
    f32x4 s = {0.0f, 0.0f, 0.0f, 0.0f};
    for (int r = 0; r < R; ++r)
        s += *(const f32x4*)(partial + (size_t)(b * R + r) * kBSpan + i0);
    f32x4 fv = *(const f32x4*)(f + (size_t)b * kBSpan + i0);
    f32x4 d  = s - fv;
    float a = d[0] * d[0] + d[1] * d[1] + d[2] * d[2] + d[3] * d[3];
    for (int off = 32; off > 0; off >>= 1) a += __shfl_down(a, off, 64);
    __shared__ float partial_s[4];
    const int lane = threadIdx.x & 63;
    const int wid  = threadIdx.x >> 6;
    if (lane == 0) partial_s[wid] = a;
    __syncthreads();
    if (threadIdx.x == 0)
        atomicAdd(norm_sum,
                  partial_s[0] + partial_s[1] + partial_s[2] + partial_s[3]);
}

// ---------------------------------------------------------------------------
// Fallback scatter (device atomics) if workspace is too small.
// ---------------------------------------------------------------------------
__global__ void scatter_dev_kernel(const float* __restrict__ K_sep,
                                   const int*   __restrict__ rows,
                                   const int*   __restrict__ cols,
                                   const float* __restrict__ u,
                                   const float* __restrict__ scale,
                                   float* __restrict__ Ku) {
    long long i = (long long)blockIdx.x * blockDim.x + threadIdx.x;
    if (i >= kNNZ) return;
    float s = scale[(int)(i >> 6)];
    atomicAdd(&Ku[rows[i]], K_sep[i] * s * u[cols[i]]);
}

__global__ void norm1_kernel(const float* __restrict__ Ku,
                             const float* __restrict__ f,
                             float* __restrict__ norm_sum) {
    float a = 0.0f;
    for (int i = blockIdx.x * blockDim.x + threadIdx.x; i < kNDOF;
         i += gridDim.x * blockDim.x) {
        float d = Ku[i] - f[i];
        a += d * d;
    }
    for (int off = 32; off > 0; off >>= 1) a += __shfl_down(a, off, 64);
    __shared__ float partial_s[4];
    const int lane = threadIdx.x & 63;
    const int wid  = threadIdx.x >> 6;
    if (lane == 0) partial_s[wid] = a;
    __syncthreads();
    if (threadIdx.x == 0)
        atomicAdd(norm_sum,
                  partial_s[0] + partial_s[1] + partial_s[2] + partial_s[3]);
}

__global__ void finalize_kernel(const float* __restrict__ acc,
                                float* __restrict__ out) {
    if (threadIdx.x == 0 && blockIdx.x == 0) {
        float rho_mean = acc[0] * (1.0f / (float)kNME);
        float vol = fmaxf(rho_mean - kVolfrac, 0.0f);
        out[0] = vol + sqrtf(acc[1]);
    }
}

}  // namespace

extern "C" void kernel_launch(void* const* d_in, const int* in_sizes, int n_in,
                              void* d_out, int out_size, void* d_ws, size_t ws_size,
                              hipStream_t stream) {
    const float* W_x   = (const float*)d_in[0];
    const float* K_sep = (const float*)d_in[1];
    const int*   idx   = (const int*)d_in[2];
    const float* u     = (const float*)d_in[3];
    const float* f     = (const float*)d_in[4];
    const int* rows = idx;
    const int* cols = idx + kNNZ;

    float* ws = (float*)d_ws;
    const size_t avail = ws_size / sizeof(float);

    // Pick (num_chunks, R, cap margin): first config that fits.
    struct Opt { int nc, R; unsigned margin; };
    const Opt opts[] = {{1, 16, 2048}, {1, 16, 1024}, {1, 8, 2048},
                        {2, 8, 2048},  {2, 8, 1024},  {4, 8, 1024},
                        {4, 4, 1024},  {8, 4, 1024}};
    int NC = -1, R = 16;
    unsigned capSub = 0;
    size_t ctrF = 0, partialF = 0;
    for (const Opt& o : opts) {
        long long perCell = kNNZ / ((long long)o.nc * kNB * o.R);
        unsigned  mc      = (unsigned)perCell + o.margin;   // multiple of 4
        size_t cf = (size_t)o.nc * kNB * o.R * kCtrStride;
        size_t pf = (size_t)kNB * o.R * kBSpan;
        size_t need = 16 + cf + pf + (size_t)kNME +
                      (size_t)kNB * o.R * (size_t)mc;       // pairs are u32
        if (need <= avail) {
            NC = o.nc; R = o.R; capSub = mc; ctrF = cf; partialF = pf;
            break;
        }
    }

    if (NC < 0) {
        // Fallback: device-atomic scatter (fits in ~3.2 MB).
        float* Ku    = ws;
        float* scale = ws + kNDOF;
        float* acc   = ws + kNDOF + kNME;
        hipMemsetAsync(ws, 0, (size_t)(kNDOF + kNME + 16) * sizeof(float), stream);
        scale_kernel<<<kNME / 256, 256, 0, stream>>>(W_x, scale, acc);
        scatter_dev_kernel<<<(int)(kNNZ / 256), 256, 0, stream>>>(
            K_sep, rows, cols, u, scale, Ku);
        norm1_kernel<<<2048, 256, 0, stream>>>(Ku, f, acc + 1);
        finalize_kernel<<<1, 64, 0, stream>>>(acc, (float*)d_out);
        return;
    }

    float*    acc      = ws;                          // [16]
    unsigned* counters = (unsigned*)(ws + 16);        // [NC][kNB*R*kCtrStride]
    float*    partial  = ws + 16 + ctrF;              // [kNB*R*kBSpan]
    float*    scale    = partial + partialF;          // [kNME]
    u32*      pairs    = (u32*)(scale + kNME);        // [kNB*R*capSub]

    // Zero acc + counters only (partial is stored, not accumulated, on c=0).
    hipMemsetAsync(ws, 0, (16 + ctrF) * sizeof(float), stream);

    scale_kernel<<<kNME / 256, 256, 0, stream>>>(W_x, scale, acc);

    const long long chunk = kNNZ / NC;
    const int prod_blocks = (int)(chunk / kEnt);
    for (int c = 0; c < NC; ++c) {
        unsigned* ctr = counters + (size_t)c * kNB * R * kCtrStride;
        producer_kernel<<<prod_blocks, 256, 0, stream>>>(
            K_sep, rows, cols, u, scale, pairs, ctr, chunk * c, capSub, R);
        consumer_kernel<<<kNB * R, 512, 0, stream>>>(
            pairs, ctr, partial, capSub, R, /*accum=*/c > 0 ? 1 : 0);
    }

    norm_kernel<<<kNB * (kBSpan / 1024), 256, 0, stream>>>(
        partial, f, acc + 1, R);

    finalize_kernel<<<1, 64, 0, stream>>>(acc, (float*)d_out);
}